// Round 1
// baseline (24916.794 us; speedup 1.0000x reference)
//
#include <hip/hip_runtime.h>
#include <math.h>

#define TT 128
#define NN 64
#define HH 1024
#define AA 16
#define KC 64

#define PD_OFF  0
#define POL_OFF (TT*NN*AA)                  /* 131072 */
#define HXS_OFF (POL_OFF + TT*NN*HH)        /* 8519680 */

// persistent per-call state (fully rewritten before read on every call)
__device__ float g_h[2][NN*HH];
__device__ float g_pol[2][NN*HH];
__device__ float g_ph[NN*HH];

__device__ __forceinline__ float sigmoidf_(float x) { return 1.0f / (1.0f + expf(-x)); }

__global__ __launch_bounds__(256) void init_kernel(const float* __restrict__ hxs) {
  int f = blockIdx.x * 256 + threadIdx.x;      // f < 65536 = NN*HH
  int n = f >> 10, j = f & 1023;
  g_h[0][f]   = hxs[n * 2 * HH + j];
  g_pol[0][f] = hxs[n * 2 * HH + HH + j];
}

// roles: bx in [0,128) -> GRU-h, [128,256) -> GRU-pol, [256,384) -> policy hidden
// block: 256 threads = 4 waves; wave = 64 lanes = 64 batch rows; each thread owns 2 output cols
__global__ __launch_bounds__(256) void step_kernel(
    int t,
    const float* __restrict__ c, const float* __restrict__ masks, const float* __restrict__ act,
    const float* __restrict__ wih_h, const float* __restrict__ whh_h,
    const float* __restrict__ bih_h, const float* __restrict__ bhh_h,
    const float* __restrict__ wih_p, const float* __restrict__ whh_p,
    const float* __restrict__ bih_p, const float* __restrict__ bhh_p,
    const float* __restrict__ pw1, const float* __restrict__ pb1,
    float* __restrict__ out)
{
  const int tid = threadIdx.x;
  const int r   = tid & 63;           // batch row
  const int jj  = tid >> 6;           // wave id 0..3
  const int bx  = blockIdx.x;
  const int role = bx >> 7;           // 0 gru-h, 1 gru-pol, 2 policy-hidden
  const int cb   = bx & 127;
  const int cur = t & 1, nxt = cur ^ 1;

  __shared__ float x_lds[KC * 65];
  __shared__ float s_lds[KC * 65];
  __shared__ float am_lds[AA * 65];
  __shared__ float m_lds[NN];

  if (tid < NN) m_lds[tid] = masks[t * NN + tid];
  __syncthreads();

  const float* __restrict__ state = (role == 1) ? g_pol[cur] : g_h[cur];

  if (role == 2) {
#pragma unroll
    for (int i = 0; i < 4; ++i) {
      int idx = tid * 4 + i;          // 0..1023
      int row = idx >> 4, kk = idx & 15;
      am_lds[kk * 65 + row] = act[(t * NN + row) * AA + kk] * m_lds[row];
    }
  }

  int c0 = __builtin_amdgcn_readfirstlane(cb * 8 + jj * 2);  // wave-uniform column
  int c1 = c0 + 1;

  float a0 = 0.f, a1 = 0.f, a2 = 0.f, a3 = 0.f, a4 = 0.f, a5 = 0.f, a6 = 0.f, a7 = 0.f;

  const float* wi = (role == 0) ? wih_h : wih_p;
  const float* wh = (role == 0) ? whh_h : whh_p;

  for (int kc0 = 0; kc0 < HH; kc0 += KC) {
    __syncthreads();
#pragma unroll
    for (int q = 0; q < 4; ++q) {
      int slot = q * 256 + tid;       // 0..1023
      int row = slot >> 4, kq = slot & 15;
      int gk = kc0 + kq * 4;
      float m = m_lds[row];
      float4 u = *reinterpret_cast<const float4*>(state + row * HH + gk);
      s_lds[(kq * 4 + 0) * 65 + row] = u.x * m;
      s_lds[(kq * 4 + 1) * 65 + row] = u.y * m;
      s_lds[(kq * 4 + 2) * 65 + row] = u.z * m;
      s_lds[(kq * 4 + 3) * 65 + row] = u.w * m;
      if (role != 2) {
        float4 v = *reinterpret_cast<const float4*>(c + (t * NN + row) * HH + gk);
        x_lds[(kq * 4 + 0) * 65 + row] = v.x;
        x_lds[(kq * 4 + 1) * 65 + row] = v.y;
        x_lds[(kq * 4 + 2) * 65 + row] = v.z;
        x_lds[(kq * 4 + 3) * 65 + row] = v.w;
      }
    }
    __syncthreads();

    if (role != 2) {
      const float* wir0 = wi + (size_t)c0 * HH + kc0;
      const float* wiz0 = wi + (size_t)(HH + c0) * HH + kc0;
      const float* win0 = wi + (size_t)(2 * HH + c0) * HH + kc0;
      const float* whr0 = wh + (size_t)c0 * HH + kc0;
      const float* whz0 = wh + (size_t)(HH + c0) * HH + kc0;
      const float* whn0 = wh + (size_t)(2 * HH + c0) * HH + kc0;
      const float* wir1 = wir0 + HH;
      const float* wiz1 = wiz0 + HH;
      const float* win1 = win0 + HH;
      const float* whr1 = whr0 + HH;
      const float* whz1 = whz0 + HH;
      const float* whn1 = whn0 + HH;
#pragma unroll 4
      for (int k = 0; k < KC; ++k) {
        float xv = x_lds[k * 65 + r];
        float sv = s_lds[k * 65 + r];
        a0 += xv * wir0[k]; a0 += sv * whr0[k];
        a1 += xv * wiz0[k]; a1 += sv * whz0[k];
        a2 += xv * win0[k];
        a3 += sv * whn0[k];
        a4 += xv * wir1[k]; a4 += sv * whr1[k];
        a5 += xv * wiz1[k]; a5 += sv * whz1[k];
        a6 += xv * win1[k];
        a7 += sv * whn1[k];
      }
    } else {
      const float* p0 = pw1 + (size_t)c0 * (HH + AA) + kc0;
      const float* p1 = p0 + (HH + AA);
#pragma unroll 4
      for (int k = 0; k < KC; ++k) {
        float sv = s_lds[k * 65 + r];
        a0 += sv * p0[k];
        a4 += sv * p1[k];
      }
    }
  }

  float m_r = m_lds[r];
  if (role != 2) {
    const float* bi = (role == 0) ? bih_h : bih_p;
    const float* bh = (role == 0) ? bhh_h : bhh_p;
    float* st_n = (role == 0) ? g_h[nxt] : g_pol[nxt];
    {
      float hm = state[r * HH + c0] * m_r;
      float rg = sigmoidf_(a0 + bi[c0] + bh[c0]);
      float z  = sigmoidf_(a1 + bi[HH + c0] + bh[HH + c0]);
      float nn = tanhf(a2 + bi[2 * HH + c0] + rg * (a3 + bh[2 * HH + c0]));
      float hv = (1.0f - z) * nn + z * hm;
      st_n[r * HH + c0] = hv;
      if (role == 1) out[POL_OFF + (size_t)(t * NN + r) * HH + c0] = hv;
    }
    {
      float hm = state[r * HH + c1] * m_r;
      float rg = sigmoidf_(a4 + bi[c1] + bh[c1]);
      float z  = sigmoidf_(a5 + bi[HH + c1] + bh[HH + c1]);
      float nn = tanhf(a6 + bi[2 * HH + c1] + rg * (a7 + bh[2 * HH + c1]));
      float hv = (1.0f - z) * nn + z * hm;
      st_n[r * HH + c1] = hv;
      if (role == 1) out[POL_OFF + (size_t)(t * NN + r) * HH + c1] = hv;
    }
  } else {
#pragma unroll
    for (int kk = 0; kk < AA; ++kk) {
      float av = am_lds[kk * 65 + r];
      a0 += av * pw1[(size_t)c0 * (HH + AA) + HH + kk];
      a4 += av * pw1[(size_t)c1 * (HH + AA) + HH + kk];
    }
    g_ph[r * HH + c0] = tanhf(a0 + pb1[c0]);
    g_ph[r * HH + c1] = tanhf(a4 + pb1[c1]);
  }
}

// p_dist_t = tanh_ph @ p_w2.T + p_b2  (64 rows x 16 outputs, K=1024)
__global__ __launch_bounds__(256) void pdist_kernel(int t, const float* __restrict__ pw2,
                                                    const float* __restrict__ pb2,
                                                    float* __restrict__ out) {
  int rrow = blockIdx.x;              // 0..63
  int tid = threadIdx.x, l = tid & 63, w = tid >> 6;
  const float* ph = g_ph + rrow * HH;
  for (int o = w; o < AA; o += 4) {
    float s = 0.f;
#pragma unroll
    for (int i = 0; i < 16; ++i) s += ph[l + 64 * i] * pw2[o * HH + l + 64 * i];
    for (int off = 32; off > 0; off >>= 1) s += __shfl_down(s, off);
    if (l == 0) out[PD_OFF + (size_t)(t * NN + rrow) * AA + o] = s + pb2[o];
  }
}

__global__ __launch_bounds__(256) void final_kernel(float* __restrict__ out) {
  int f = blockIdx.x * 256 + threadIdx.x;   // f < 131072
  int n = f >> 11, j = f & 2047;
  // after 128 steps the live buffer is index 0
  out[HXS_OFF + f] = (j < HH) ? g_h[0][n * HH + j] : g_pol[0][n * HH + (j - HH)];
}

extern "C" void kernel_launch(void* const* d_in, const int* in_sizes, int n_in,
                              void* d_out, int out_size, void* d_ws, size_t ws_size,
                              hipStream_t stream) {
  const float* c     = (const float*)d_in[0];
  const float* hxs   = (const float*)d_in[1];
  const float* masks = (const float*)d_in[2];
  const float* act   = (const float*)d_in[3];
  const float* wih_h = (const float*)d_in[4];
  const float* whh_h = (const float*)d_in[5];
  const float* bih_h = (const float*)d_in[6];
  const float* bhh_h = (const float*)d_in[7];
  const float* wih_p = (const float*)d_in[8];
  const float* whh_p = (const float*)d_in[9];
  const float* bih_p = (const float*)d_in[10];
  const float* bhh_p = (const float*)d_in[11];
  const float* pw1   = (const float*)d_in[12];
  const float* pb1   = (const float*)d_in[13];
  const float* pw2   = (const float*)d_in[14];
  const float* pb2   = (const float*)d_in[15];
  float* out = (float*)d_out;

  init_kernel<<<256, 256, 0, stream>>>(hxs);
  for (int t = 0; t < TT; ++t) {
    step_kernel<<<384, 256, 0, stream>>>(t, c, masks, act,
                                         wih_h, whh_h, bih_h, bhh_h,
                                         wih_p, whh_p, bih_p, bhh_p,
                                         pw1, pb1, out);
    pdist_kernel<<<64, 256, 0, stream>>>(t, pw2, pb2, out);
  }
  final_kernel<<<512, 256, 0, stream>>>(out);
}

// Round 2
// 2248.815 us; speedup vs baseline: 11.0800x; 11.0800x over previous
//
#include <hip/hip_runtime.h>
#include <hip/hip_bf16.h>
#include <math.h>

#define TT 128
#define NN 64
#define HH 1024
#define AA 16
#define G3 3072          /* 3*HH */
#define NC 6144          /* combined gi cols (2 GRUs x 3 gates x 1024) */
#define PK 1056          /* padded policy K stride (1040 -> 1056, zero tail) */

#define PD_OFF  0
#define POL_OFF (TT*NN*AA)                  /* 131072 */
#define HXS_OFF (POL_OFF + TT*NN*HH)        /* 8519680 */

typedef __attribute__((ext_vector_type(8))) short short8;
typedef __attribute__((ext_vector_type(4))) float f32x4;

// ---- persistent device buffers (fully rewritten every call) ----
__device__ __align__(16) __hip_bfloat16 g_c_bf[TT*NN*HH];       // 16 MB
__device__ __align__(16) __hip_bfloat16 g_wihc_bf[NC*HH];       // 12.6 MB (wih_h rows 0..3071, wih_p 3072..6143)
__device__ __align__(16) __hip_bfloat16 g_whh_bf[2][G3*HH];     // 12.6 MB
__device__ __align__(16) __hip_bfloat16 g_pw1_bf[HH*PK];        // 2.2 MB ([1024][1056], cols >=1040 zero)
__device__ __align__(16) __hip_bfloat16 g_pw2_bf[AA*HH];        // 32 KB
__device__ float g_gi[(size_t)TT*NN*NC];                        // 201 MB fp32 precomputed gi
__device__ float g_h[NN*HH];                                    // fp32 h state
__device__ float g_pol[NN*HH];                                  // fp32 pol state
__device__ __align__(16) __hip_bfloat16 g_pin[2][NN*PK];        // masked [h | a | 0] bf16 (A operand)
__device__ __align__(16) __hip_bfloat16 g_polm[2][NN*HH];       // masked pol bf16
__device__ __align__(16) __hip_bfloat16 g_ph[2][NN*HH];         // tanh(policy hidden) bf16

__device__ __forceinline__ float sigmoidf_(float x) { return 1.0f / (1.0f + __expf(-x)); }
__device__ __forceinline__ float tanhf_(float x) {
  float e = __expf(2.0f * x);
  return 1.0f - 2.0f / (e + 1.0f);        // graceful at +/-inf
}

// ---------------- conversions (fp32 -> bf16 mirrors) ----------------
__global__ __launch_bounds__(256) void conv_all(
    const float* __restrict__ c,
    const float* __restrict__ wih_h, const float* __restrict__ wih_p,
    const float* __restrict__ whh_h, const float* __restrict__ whh_p,
    const float* __restrict__ pw1, const float* __restrict__ pw2)
{
  size_t i = (size_t)blockIdx.x * 256 + threadIdx.x;
  size_t stride = (size_t)gridDim.x * 256;
  for (size_t f = i; f < (size_t)TT*NN*HH; f += stride) g_c_bf[f] = __float2bfloat16(c[f]);
  for (size_t f = i; f < (size_t)G3*HH; f += stride) {
    g_wihc_bf[f]                 = __float2bfloat16(wih_h[f]);
    g_wihc_bf[(size_t)G3*HH + f] = __float2bfloat16(wih_p[f]);
    g_whh_bf[0][f] = __float2bfloat16(whh_h[f]);
    g_whh_bf[1][f] = __float2bfloat16(whh_p[f]);
  }
  for (size_t f = i; f < (size_t)HH*PK; f += stride) {
    int o = (int)(f / PK), j = (int)(f % PK);
    g_pw1_bf[f] = (j < HH + AA) ? __float2bfloat16(pw1[(size_t)o*(HH+AA) + j]) : __float2bfloat16(0.0f);
  }
  for (size_t f = i; f < (size_t)AA*HH; f += stride) g_pw2_bf[f] = __float2bfloat16(pw2[f]);
}

__global__ __launch_bounds__(256) void init_kernel(const float* __restrict__ hxs,
                                                   const float* __restrict__ masks,
                                                   const float* __restrict__ act) {
  int f = blockIdx.x * 256 + threadIdx.x;      // exactly NN*HH threads
  int n = f >> 10, j = f & 1023;
  float m0 = masks[n];                         // masks[t=0, n]
  float hv = hxs[n * 2 * HH + j];
  float pv = hxs[n * 2 * HH + HH + j];
  g_h[f] = hv;
  g_pol[f] = pv;
  g_pin[0][n * PK + j]  = __float2bfloat16(hv * m0);
  g_polm[0][n * HH + j] = __float2bfloat16(pv * m0);
  if (f < NN * 32) {
    int n2 = f >> 5, q = f & 31;
    float m2 = masks[n2];
    if (q < AA) {
      g_pin[0][n2 * PK + HH + q] = __float2bfloat16(act[n2 * AA + q] * m2);
    } else {
      g_pin[0][n2 * PK + HH + AA + (q - AA)] = __float2bfloat16(0.0f);
      g_pin[1][n2 * PK + HH + AA + (q - AA)] = __float2bfloat16(0.0f);
    }
  }
}

// ---------------- precompute gi = c @ [wih_h;wih_p].T  (bf16 MFMA, fp32 out) ----------------
// tiles 64x64, BK=64, 4 waves (wave = 16-row strip x 64 cols)
__global__ __launch_bounds__(256) void pre_gemm() {
  __shared__ __align__(16) __hip_bfloat16 As[64 * 72];
  __shared__ __align__(16) __hip_bfloat16 Bs[64 * 72];
  const int tid = threadIdx.x, l = tid & 63, w = tid >> 6;
  const int bm = blockIdx.x / 96, bn = blockIdx.x % 96;
  const __hip_bfloat16* A = g_c_bf    + (size_t)bm * 64 * HH;
  const __hip_bfloat16* B = g_wihc_bf + (size_t)bn * 64 * HH;
  f32x4 acc[4] = {};
  for (int kt = 0; kt < 16; ++kt) {
    const int kc = kt * 64;
    __syncthreads();
#pragma unroll
    for (int ch = tid; ch < 512; ch += 256) {
      int rr = ch >> 3, kq = ch & 7;
      *(short8*)(&As[rr * 72 + kq * 8]) = *(const short8*)(A + (size_t)rr * HH + kc + kq * 8);
      *(short8*)(&Bs[rr * 72 + kq * 8]) = *(const short8*)(B + (size_t)rr * HH + kc + kq * 8);
    }
    __syncthreads();
#pragma unroll
    for (int ks = 0; ks < 2; ++ks) {
      short8 a = *(const short8*)(&As[(w * 16 + (l & 15)) * 72 + ks * 32 + (l >> 4) * 8]);
#pragma unroll
      for (int nf = 0; nf < 4; ++nf) {
        short8 b = *(const short8*)(&Bs[(nf * 16 + (l & 15)) * 72 + ks * 32 + (l >> 4) * 8]);
        acc[nf] = __builtin_amdgcn_mfma_f32_16x16x32_bf16(a, b, acc[nf], 0, 0, 0);
      }
    }
  }
#pragma unroll
  for (int nf = 0; nf < 4; ++nf)
#pragma unroll
    for (int reg = 0; reg < 4; ++reg) {
      int row = bm * 64 + w * 16 + ((l >> 4) * 4 + reg);
      int col = bn * 64 + nf * 16 + (l & 15);
      g_gi[(size_t)row * NC + col] = acc[nf][reg];
    }
}

// ---------------- per-step kernel ----------------
// grid 192: bx 0..63 GRU-h, 64..127 GRU-pol, 128..191 policy-hidden (bx 128 also does pdist[t-1] + a_m[t+1])
__global__ __launch_bounds__(256) void step_kernel(
    int t, const float* __restrict__ masks, const float* __restrict__ act,
    const float* __restrict__ bih_h, const float* __restrict__ bhh_h,
    const float* __restrict__ bih_p, const float* __restrict__ bhh_p,
    const float* __restrict__ pb1, const float* __restrict__ pb2,
    float* __restrict__ out)
{
  __shared__ __align__(16) __hip_bfloat16 smem[24960];   // GRU: [48][520], policy: [16][1064]
  const int tid = threadIdx.x, l = tid & 63, w = tid >> 6;
  const int bx = blockIdx.x;
  const int cur = t & 1, nxt = cur ^ 1;

  if (bx < 128) {
    const int gru = bx >> 6;
    const int c0 = (bx & 63) * 16;
    const __hip_bfloat16* Abase = (gru == 0) ? g_pin[cur] : g_polm[cur];
    const int astr = (gru == 0) ? PK : HH;
    const __hip_bfloat16* W = g_whh_bf[gru];
    f32x4 acc0 = {}, acc1 = {}, acc2 = {};

    for (int half = 0; half < 2; ++half) {
      const int kbase = half * 512;
      __syncthreads();
      // stage 48 weight rows x 512 K into LDS (stride 520 spreads b128 bank starts)
      for (int ch = tid; ch < 3072; ch += 256) {
        int rr = ch >> 6, kq = ch & 63;
        int g = rr >> 4, j = rr & 15;
        *(short8*)(&smem[rr * 520 + kq * 8]) =
            *(const short8*)(W + (size_t)(g * HH + c0 + j) * HH + kbase + kq * 8);
      }
      __syncthreads();
#pragma unroll 4
      for (int k32 = 0; k32 < 16; ++k32) {
        short8 a = *(const short8*)(Abase + (size_t)(w * 16 + (l & 15)) * astr + kbase + k32 * 32 + (l >> 4) * 8);
        short8 b0 = *(const short8*)(&smem[( 0 + (l & 15)) * 520 + k32 * 32 + (l >> 4) * 8]);
        short8 b1 = *(const short8*)(&smem[(16 + (l & 15)) * 520 + k32 * 32 + (l >> 4) * 8]);
        short8 b2 = *(const short8*)(&smem[(32 + (l & 15)) * 520 + k32 * 32 + (l >> 4) * 8]);
        acc0 = __builtin_amdgcn_mfma_f32_16x16x32_bf16(a, b0, acc0, 0, 0, 0);
        acc1 = __builtin_amdgcn_mfma_f32_16x16x32_bf16(a, b1, acc1, 0, 0, 0);
        acc2 = __builtin_amdgcn_mfma_f32_16x16x32_bf16(a, b2, acc2, 0, 0, 0);
      }
    }

    // epilogue: lane holds r/z/n pre-acts for col, rows w*16 + 4*(l>>4) + reg
    const float* bi = (gru == 0) ? bih_h : bih_p;
    const float* bh = (gru == 0) ? bhh_h : bhh_p;
    float* st = (gru == 0) ? g_h : g_pol;
    const int col = c0 + (l & 15);
    const float bir = bi[col],        bhr = bh[col];
    const float biz = bi[HH + col],   bhz = bh[HH + col];
    const float bin = bi[2*HH + col], bhn = bh[2*HH + col];
#pragma unroll
    for (int reg = 0; reg < 4; ++reg) {
      int row = w * 16 + (l >> 4) * 4 + reg;
      float m = masks[t * NN + row];
      const float* gi = g_gi + (size_t)(t * NN + row) * NC + gru * G3;
      float hm = st[row * HH + col] * m;
      float rg  = sigmoidf_(gi[col]        + acc0[reg] + bir + bhr);
      float z   = sigmoidf_(gi[HH + col]   + acc1[reg] + biz + bhz);
      float nn2 = tanhf_  (gi[2*HH + col]  + bin + rg * (acc2[reg] + bhn));
      float hv = (1.0f - z) * nn2 + z * hm;
      st[row * HH + col] = hv;
      float mn = (t < TT - 1) ? masks[(t + 1) * NN + row] : 1.0f;
      if (gru == 0) {
        g_pin[nxt][row * PK + col] = __float2bfloat16(hv * mn);
      } else {
        g_polm[nxt][row * HH + col] = __float2bfloat16(hv * mn);
        out[POL_OFF + (size_t)(t * NN + row) * HH + col] = hv;
      }
    }
  } else {
    const int c0 = (bx - 128) * 16;
    if (bx == 128) {
      // pdist for step t-1 (reads ph buffer (t-1)&1 == nxt)
      if (t > 0) {
        f32x4 pa = {};
        const __hip_bfloat16* PH = g_ph[nxt];
#pragma unroll 4
        for (int k32 = 0; k32 < 32; ++k32) {
          short8 a = *(const short8*)(PH + (size_t)(w * 16 + (l & 15)) * HH + k32 * 32 + (l >> 4) * 8);
          short8 b = *(const short8*)(g_pw2_bf + (size_t)(l & 15) * HH + k32 * 32 + (l >> 4) * 8);
          pa = __builtin_amdgcn_mfma_f32_16x16x32_bf16(a, b, pa, 0, 0, 0);
        }
        int o = l & 15;
        float bb = pb2[o];
#pragma unroll
        for (int reg = 0; reg < 4; ++reg) {
          int row = w * 16 + (l >> 4) * 4 + reg;
          out[PD_OFF + (size_t)((t - 1) * NN + row) * AA + o] = pa[reg] + bb;
        }
      }
      // a_m for step t+1 into the other pin buffer (disjoint cols vs GRU-h writers)
      if (t < TT - 1) {
        for (int i = tid; i < NN * AA; i += 256) {
          int rr = i >> 4, j = i & 15;
          float m = masks[(t + 1) * NN + rr];
          g_pin[nxt][rr * PK + HH + j] = __float2bfloat16(act[((t + 1) * NN + rr) * AA + j] * m);
        }
      }
    }
    // policy hidden: ph = tanh(p_in @ pw1.T + b1), cols c0..c0+15, K = 1056 (zero-padded)
    for (int ch = tid; ch < 2112; ch += 256) {
      int rr = ch / 132, kq = ch % 132;
      *(short8*)(&smem[rr * 1064 + kq * 8]) =
          *(const short8*)(g_pw1_bf + (size_t)(c0 + rr) * PK + kq * 8);
    }
    __syncthreads();
    f32x4 acc = {};
#pragma unroll 4
    for (int k32 = 0; k32 < 33; ++k32) {
      short8 a = *(const short8*)(g_pin[cur] + (size_t)(w * 16 + (l & 15)) * PK + k32 * 32 + (l >> 4) * 8);
      short8 b = *(const short8*)(&smem[(l & 15) * 1064 + k32 * 32 + (l >> 4) * 8]);
      acc = __builtin_amdgcn_mfma_f32_16x16x32_bf16(a, b, acc, 0, 0, 0);
    }
    const int col = c0 + (l & 15);
    const float b1v = pb1[col];
#pragma unroll
    for (int reg = 0; reg < 4; ++reg) {
      int row = w * 16 + (l >> 4) * 4 + reg;
      g_ph[cur][row * HH + col] = __float2bfloat16(tanhf_(acc[reg] + b1v));
    }
  }
}

// ---------------- final: hxs output + pdist[127] ----------------
__global__ __launch_bounds__(256) void final_kernel(const float* __restrict__ pb2,
                                                    float* __restrict__ out) {
  const int bx = blockIdx.x, tid = threadIdx.x;
  if (bx < 512) {
    int f = bx * 256 + tid;                 // < 131072
    int n = f >> 11, j = f & 2047;
    out[HXS_OFF + f] = (j < HH) ? g_h[n * HH + j] : g_pol[n * HH + (j - HH)];
  } else {
    const int l = tid & 63, w = tid >> 6;
    f32x4 pa = {};
    const __hip_bfloat16* PH = g_ph[1];     // 127 & 1
#pragma unroll 4
    for (int k32 = 0; k32 < 32; ++k32) {
      short8 a = *(const short8*)(PH + (size_t)(w * 16 + (l & 15)) * HH + k32 * 32 + (l >> 4) * 8);
      short8 b = *(const short8*)(g_pw2_bf + (size_t)(l & 15) * HH + k32 * 32 + (l >> 4) * 8);
      pa = __builtin_amdgcn_mfma_f32_16x16x32_bf16(a, b, pa, 0, 0, 0);
    }
    int o = l & 15;
    float bb = pb2[o];
#pragma unroll
    for (int reg = 0; reg < 4; ++reg) {
      int row = w * 16 + (l >> 4) * 4 + reg;
      out[PD_OFF + (size_t)(127 * NN + row) * AA + o] = pa[reg] + bb;
    }
  }
}

extern "C" void kernel_launch(void* const* d_in, const int* in_sizes, int n_in,
                              void* d_out, int out_size, void* d_ws, size_t ws_size,
                              hipStream_t stream) {
  const float* c     = (const float*)d_in[0];
  const float* hxs   = (const float*)d_in[1];
  const float* masks = (const float*)d_in[2];
  const float* act   = (const float*)d_in[3];
  const float* wih_h = (const float*)d_in[4];
  const float* whh_h = (const float*)d_in[5];
  const float* bih_h = (const float*)d_in[6];
  const float* bhh_h = (const float*)d_in[7];
  const float* wih_p = (const float*)d_in[8];
  const float* whh_p = (const float*)d_in[9];
  const float* bih_p = (const float*)d_in[10];
  const float* bhh_p = (const float*)d_in[11];
  const float* pw1   = (const float*)d_in[12];
  const float* pb1   = (const float*)d_in[13];
  const float* pw2   = (const float*)d_in[14];
  const float* pb2   = (const float*)d_in[15];
  float* out = (float*)d_out;

  conv_all<<<4096, 256, 0, stream>>>(c, wih_h, wih_p, whh_h, whh_p, pw1, pw2);
  init_kernel<<<256, 256, 0, stream>>>(hxs, masks, act);
  pre_gemm<<<12288, 256, 0, stream>>>();
  for (int t = 0; t < TT; ++t) {
    step_kernel<<<192, 256, 0, stream>>>(t, masks, act, bih_h, bhh_h, bih_p, bhh_p, pb1, pb2, out);
  }
  final_kernel<<<513, 256, 0, stream>>>(pb2, out);
}